// Round 14
// baseline (1195.585 us; speedup 1.0000x reference)
//
#include <hip/hip_runtime.h>
#include <stdint.h>

typedef unsigned short u16;
typedef unsigned int   u32;
typedef float f32x4  __attribute__((ext_vector_type(4)));
typedef short bf16x8 __attribute__((ext_vector_type(8)));

#define NSEQ 800
#define TOUT 12
#define NC   9
#define LOG2E  1.44269504088896340736f
#define LOG2E2 2.88539008177792681472f

// ---- LDS (256-thread block = 4 waves = 4 gate-quarters, 16 seqs) ----
// H ping-pong, separate hi/lo: PING hi@0 lo@2048, PONG hi@4096 lo@6144.
// k-perm: k=kq*8+j, ht=((kq>>2)<<1)|(j&1), n=((j>>1)&3)|((kq&3)<<2)  (hid=ht*16+n)
// cell(seq,kq) @ seq*128 + rot*16 (+j*2), rot=(kq+seq+(seq>>3))&7
// Encoder: 1 barrier/step (read bufA, write bufB, swap, sync).
// Decoder adds vs-scratch barrier pair (safe cross-wave v reduce).
#define PONG 4096
#define VSCR 8192
#define LDS_TOTAL 8448

__device__ __forceinline__ u16 f2bf(float f){ union{float f;u32 i;}v; v.f=f; u32 x=v.i; return (u16)((x + 0x7fffu + ((x>>16)&1u))>>16); }

union BXU { uint4 u; bf16x8 v; };

__global__ __launch_bounds__(256, 4) void rnn_kernel(
  const float* __restrict__ X,
  const float* __restrict__ cw2, const float* __restrict__ cw3, const float* __restrict__ cw4,
  const float* __restrict__ cbv,
  const float* __restrict__ Ewih, const float* __restrict__ Ewhh,
  const float* __restrict__ Ebih, const float* __restrict__ Ebhh,
  const float* __restrict__ Dwih, const float* __restrict__ Dwhh,
  const float* __restrict__ Dbih, const float* __restrict__ Dbhh,
  const float* __restrict__ Lw,   const float* __restrict__ Lb,
  const float* __restrict__ emb,
  float* __restrict__ out)
{
  __shared__ char LDSC[LDS_TOTAL];
  const int tid = threadIdx.x;
  const int ht  = tid >> 6;      // wave id = gate-quarter
  const int l   = tid & 63;
  const int q   = l >> 4;
  const int n   = l & 15;
  const int r   = blockIdx.y;
  const int seqbase = blockIdx.x*16;
  const int hid = ht*16 + n;

  const int Kc[NC]={2,2,2,3,3,3,4,4,4};
  const int Dc[NC]={1,2,4,1,2,4,1,2,4};
  const int K = Kc[r], D = Dc[r];
  const int L = 15 - (K-1)*D;

  // zero PING (hi+lo = 4096 B = 256 threads x 16 B)
  *(uint4*)(LDSC + tid*16) = uint4{0,0,0,0};

  // ---- whh B-frags in registers (6 frags, k-permuted, exp2-scaled) ----
  bf16x8 bhR[2], bhZ[2], bhN[2];
  auto gather_bh = [&](const float* __restrict__ whh){
    const float* pR = whh + (      hid)*64;
    const float* pZ = whh + ( 64 + hid)*64;
    const float* pN = whh + (128 + hid)*64;
    #pragma unroll
    for (int ks=0; ks<2; ks++){
      u32 wR[4]={0,0,0,0}, wZ[4]={0,0,0,0}, wN[4]={0,0,0,0};
      #pragma unroll
      for (int j=0;j<8;j++){
        int hh = (((ks<<1)|(j&1))<<4) | ((j>>1)&3) | (q<<2);
        u32 sh = (u32)(j&1)*16;
        wR[j>>1] |= (u32)f2bf(LOG2E  * pR[hh]) << sh;
        wZ[j>>1] |= (u32)f2bf(LOG2E  * pZ[hh]) << sh;
        wN[j>>1] |= (u32)f2bf(LOG2E2 * pN[hh]) << sh;
      }
      BXU t;
      t.u = uint4{wR[0],wR[1],wR[2],wR[3]}; bhR[ks]=t.v;
      t.u = uint4{wZ[0],wZ[1],wZ[2],wZ[3]}; bhZ[ks]=t.v;
      t.u = uint4{wN[0],wN[1],wN[2],wN[3]}; bhN[ks]=t.v;
    }
  };
  gather_bh(Ewhh + (size_t)r*192*64);

  // ---- x B-frags (conv folded into wih), registers, exp2-scaled ----
  BXU bxR, bxZ, bxN;
  {
    const float* wih = Ewih + r*192*8;
    const float* cw  = (r<3) ? (cw2 + r*128) : (r<6) ? (cw3 + (r-3)*192) : (cw4 + (r-6)*256);
    bxR.u = uint4{0,0,0,0}; bxZ.u = uint4{0,0,0,0}; bxN.u = uint4{0,0,0,0};
    if (q < K){
      const float* rowR = wih + (      hid)*8;
      const float* rowZ = wih + ( 64 + hid)*8;
      const float* rowN = wih + (128 + hid)*8;
      u32 aR[4]={0,0,0,0}, aZ[4]={0,0,0,0}, aN[4]={0,0,0,0};
      #pragma unroll
      for (int j=0;j<8;j++){
        float sR=0.f,sZ=0.f,sN=0.f;
        #pragma unroll
        for (int o=0;o<8;o++){
          float c = cw[(o*8+j)*K + q];
          sR += rowR[o]*c; sZ += rowZ[o]*c; sN += rowN[o]*c;
        }
        u32 sh = (u32)(j&1)*16;
        aR[j>>1] |= (u32)f2bf(LOG2E *sR) << sh;
        aZ[j>>1] |= (u32)f2bf(LOG2E *sZ) << sh;
        aN[j>>1] |= (u32)f2bf(LOG2E2*sN) << sh;
      }
      bxR.u = uint4{aR[0],aR[1],aR[2],aR[3]};
      bxZ.u = uint4{aZ[0],aZ[1],aZ[2],aZ[3]};
      bxN.u = uint4{aN[0],aN[1],aN[2],aN[3]};
    }
  }

  // ---- biases (scaled), conv bias folded ----
  float bR, bZ, bNi, bNh_;
  {
    const float* bi = Ebih + r*192; const float* bh2 = Ebhh + r*192;
    const float* wih = Ewih + r*192*8; const float* cb = cbv + r*8;
    float cR=0.f,cZ=0.f,cN=0.f;
    #pragma unroll
    for (int o=0;o<8;o++){
      cR += wih[hid*8+o]*cb[o];
      cZ += wih[(64+hid)*8+o]*cb[o];
      cN += wih[(128+hid)*8+o]*cb[o];
    }
    bR  = LOG2E  * (bi[hid]     + bh2[hid]     + cR);
    bZ  = LOG2E  * (bi[64+hid]  + bh2[64+hid]  + cZ);
    bNi = LOG2E2 * (bi[128+hid]                + cN);
    bNh_= LOG2E2 *                bh2[128+hid];
  }

  float hO[4] = {0.f,0.f,0.f,0.f};

  // step-invariant LDS addresses
  const int ra0 = n*128 + ((((  q) + n + (n>>3))&7)<<4);
  const int ra1 = n*128 + ((((4+q) + n + (n>>3))&7)<<4);
  const int kqw = ((ht>>1)<<2) | (n>>2);
  const int jw2 = ((((n&3)<<1) | (ht&1)) << 1);
  int wa[4];
  #pragma unroll
  for (int i=0;i<4;i++){
    int seq = q*4+i;
    wa[i] = seq*128 + (((kqw + seq + (seq>>3))&7)<<4) + jw2;
  }
  int hr = 0, hw = PONG;

  // ---- one GRU step; caller must __syncthreads() after ----
  auto step_core = [&](bf16x8 ax){
    const char* rp = LDSC + hr;
    bf16x8 ahi0 = *(const bf16x8*)(rp + ra0);
    bf16x8 ahi1 = *(const bf16x8*)(rp + ra1);
    bf16x8 alo0 = *(const bf16x8*)(rp + 2048 + ra0);
    bf16x8 alo1 = *(const bf16x8*)(rp + 2048 + ra1);
    f32x4 aR  = f32x4{bR,bR,bR,bR};
    f32x4 aZ  = f32x4{bZ,bZ,bZ,bZ};
    f32x4 aNi = f32x4{bNi,bNi,bNi,bNi};
    f32x4 aNh = f32x4{bNh_,bNh_,bNh_,bNh_};
    aR = __builtin_amdgcn_mfma_f32_16x16x32_bf16(ahi0, bhR[0], aR,0,0,0);
    aR = __builtin_amdgcn_mfma_f32_16x16x32_bf16(alo0, bhR[0], aR,0,0,0);
    aR = __builtin_amdgcn_mfma_f32_16x16x32_bf16(ahi1, bhR[1], aR,0,0,0);
    aR = __builtin_amdgcn_mfma_f32_16x16x32_bf16(alo1, bhR[1], aR,0,0,0);
    aR = __builtin_amdgcn_mfma_f32_16x16x32_bf16(ax,   bxR.v,  aR,0,0,0);
    aZ = __builtin_amdgcn_mfma_f32_16x16x32_bf16(ahi0, bhZ[0], aZ,0,0,0);
    aZ = __builtin_amdgcn_mfma_f32_16x16x32_bf16(alo0, bhZ[0], aZ,0,0,0);
    aZ = __builtin_amdgcn_mfma_f32_16x16x32_bf16(ahi1, bhZ[1], aZ,0,0,0);
    aZ = __builtin_amdgcn_mfma_f32_16x16x32_bf16(alo1, bhZ[1], aZ,0,0,0);
    aZ = __builtin_amdgcn_mfma_f32_16x16x32_bf16(ax,   bxZ.v,  aZ,0,0,0);
    aNh= __builtin_amdgcn_mfma_f32_16x16x32_bf16(ahi0, bhN[0], aNh,0,0,0);
    aNh= __builtin_amdgcn_mfma_f32_16x16x32_bf16(alo0, bhN[0], aNh,0,0,0);
    aNh= __builtin_amdgcn_mfma_f32_16x16x32_bf16(ahi1, bhN[1], aNh,0,0,0);
    aNh= __builtin_amdgcn_mfma_f32_16x16x32_bf16(alo1, bhN[1], aNh,0,0,0);
    aNi= __builtin_amdgcn_mfma_f32_16x16x32_bf16(ax,   bxN.v,  aNi,0,0,0);
    char* wp = LDSC + hw;
    #pragma unroll
    for (int i=0;i<4;i++){
      float rr = __builtin_amdgcn_rcpf(1.f + __builtin_amdgcn_exp2f(-aR[i]));
      float zz = __builtin_amdgcn_rcpf(1.f + __builtin_amdgcn_exp2f(-aZ[i]));
      float y  = aNi[i] + rr*aNh[i];
      float nn = 1.f - 2.f*__builtin_amdgcn_rcpf(__builtin_amdgcn_exp2f(y) + 1.f);
      float hn = nn + zz*(hO[i]-nn);
      hO[i] = hn;
      u32 hnb = __float_as_uint(hn);
      float hif = __uint_as_float(hnb & 0xffff0000u);
      u32 reb = __float_as_uint(hn - hif);
      *(u16*)(wp + wa[i])        = (u16)(hnb>>16);
      *(u16*)(wp + 2048 + wa[i]) = (u16)(reb>>16);
    }
    int t_ = hr; hr = hw; hw = t_;
  };

  // ---------- encoder ----------
  const float* xb = X + (size_t)(seqbase + n)*120 + ((q<K)? q:0)*D*8;
  __syncthreads();
  #pragma unroll 1
  for (int t=0; t<L; t++){
    float4 v0 = *(const float4*)(xb + t*8);
    float4 v1 = *(const float4*)(xb + t*8 + 4);
    BXU a;
    a.u.x = __builtin_amdgcn_perm(__float_as_uint(v0.y), __float_as_uint(v0.x), 0x07060302u);
    a.u.y = __builtin_amdgcn_perm(__float_as_uint(v0.w), __float_as_uint(v0.z), 0x07060302u);
    a.u.z = __builtin_amdgcn_perm(__float_as_uint(v1.y), __float_as_uint(v1.x), 0x07060302u);
    a.u.w = __builtin_amdgcn_perm(__float_as_uint(v1.w), __float_as_uint(v1.z), 0x07060302u);
    step_core(a.v);
    __syncthreads();
  }

  // ---------- decoder weight switch (registers only) ----------
  gather_bh(Dwhh + (size_t)r*192*64);
  {
    const float* dwih = Dwih + r*192;
    bxR.u = uint4{0,0,0,0}; bxZ.u = uint4{0,0,0,0}; bxN.u = uint4{0,0,0,0};
    if (q==0){
      bxR.u.x = (u32)f2bf(LOG2E *dwih[hid]);
      bxZ.u.x = (u32)f2bf(LOG2E *dwih[64+hid]);
      bxN.u.x = (u32)f2bf(LOG2E2*dwih[128+hid]);
    }
    const float* bi = Dbih + r*192; const float* bh2 = Dbhh + r*192;
    bR  = LOG2E  * (bi[hid]     + bh2[hid]);
    bZ  = LOG2E  * (bi[64+hid]  + bh2[64+hid]);
    bNi = LOG2E2 *  bi[128+hid];
    bNh_= LOG2E2 *  bh2[128+hid];
  }
  const float lwr = Lw[r*64 + hid];
  const float lb_ = Lb[r];
  float wgt;
  {
    int nb = (seqbase + n) % NSEQ;
    float e[NC], mx = -1e30f;
    #pragma unroll
    for (int c=0;c<NC;c++){ e[c] = emb[nb*NC+c]; mx = fmaxf(mx, e[c]); }
    float sm = 0.f;
    #pragma unroll
    for (int c=0;c<NC;c++) sm += __expf(e[c]-mx);
    wgt = __expf(e[r]-mx) / sm;
  }
  float lv = X[(size_t)(seqbase + n)*120 + 112];   // last0 for seq=n

  // ---------- decoder (2 barriers/step: h + vs ordering) ----------
  #pragma unroll 1
  for (int t=0; t<TOUT; t++){
    BXU a; a.u = uint4{0,0,0,0};
    if (q==0) a.u.x = __float_as_uint(lv) >> 16;   // bf16-trunc(lv) at k=0
    step_core(a.v);
    float p0 = lwr*hO[0], p1 = lwr*hO[1], p2 = lwr*hO[2], p3 = lwr*hO[3];
    #pragma unroll
    for (int m=1; m<16; m<<=1){
      p0 += __shfl_xor(p0,m,64); p1 += __shfl_xor(p1,m,64);
      p2 += __shfl_xor(p2,m,64); p3 += __shfl_xor(p3,m,64);
    }
    __syncthreads();   // h-hazard + prior vs reads complete
    if (n==0){
      float* vs = (float*)(LDSC + VSCR);
      vs[ht*16 + q*4 + 0] = p0; vs[ht*16 + q*4 + 1] = p1;
      vs[ht*16 + q*4 + 2] = p2; vs[ht*16 + q*4 + 3] = p3;
    }
    __syncthreads();   // vs writes visible
    const float* vs = (const float*)(LDSC + VSCR);
    float v = vs[n] + vs[16+n] + vs[32+n] + vs[48+n] + lb_;
    lv = v;
    if (ht==0 && l<16) atomicAdd(out + (size_t)(seqbase+l)*TOUT + t, wgt*v);
  }
}

extern "C" void kernel_launch(void* const* d_in, const int* in_sizes, int n_in,
                              void* d_out, int out_size, void* d_ws, size_t ws_size,
                              hipStream_t stream)
{
  float* out = (float*)d_out;
  hipMemsetAsync(out, 0, (size_t)out_size*sizeof(float), stream);

  dim3 g(51200/16, NC);   // 3200 x 9 blocks; 16 seqs per block, 4 waves (gate-quarters)
  rnn_kernel<<<g, 256, 0, stream>>>(
    (const float*)d_in[1],
    (const float*)d_in[2], (const float*)d_in[3], (const float*)d_in[4],
    (const float*)d_in[5],
    (const float*)d_in[6], (const float*)d_in[7], (const float*)d_in[8], (const float*)d_in[9],
    (const float*)d_in[10],(const float*)d_in[11],(const float*)d_in[12],(const float*)d_in[13],
    (const float*)d_in[14],(const float*)d_in[15],
    (const float*)d_in[16],
    out);
}